// Round 1
// baseline (3272.947 us; speedup 1.0000x reference)
//
#include <hip/hip_runtime.h>
#include <math.h>

#define L_SEQ 2048
#define D_MODEL 3072
#define NH 32
#define HDIM 96
#define OPROJ 9216

using f4 = __attribute__((ext_vector_type(4))) float;
using f2 = __attribute__((ext_vector_type(2))) float;

// ---------------------------------------------------------------------------
// C[m][n] = sum_k A[m*K+k] * B[n*K+k]   (both operands K-contiguous, "NT")
// 128x128 block tile, BK=16, 256 threads, 8x8 per thread, wave-tiled 2x2.
// LDS rows padded to 132 floats: stagger=4 banks -> <=2-way conflicts (free).
// ---------------------------------------------------------------------------
__global__ __launch_bounds__(256, 2) void sgemm_nt(const float* __restrict__ A,
                                                   const float* __restrict__ B,
                                                   float* __restrict__ C,
                                                   int M, int N, int K) {
    __shared__ float As[16][132];
    __shared__ float Bs[16][132];
    const int t = threadIdx.x;
    const int bm = blockIdx.y * 128;
    const int bn = blockIdx.x * 128;
    const int wave = t >> 6, lane = t & 63;
    const int wx = wave & 1, wy = wave >> 1;
    const int lx = lane & 7, ly = lane >> 3;
    const int row0 = wy * 64 + ly * 8;
    const int col0 = wx * 64 + lx * 8;

    float acc[8][8] = {};

    for (int k0 = 0; k0 < K; k0 += 16) {
        // stage 128x16 of A and B (512 float4 each / 256 threads = 2 each)
#pragma unroll
        for (int i = 0; i < 2; i++) {
            const int v = t + i * 256;
            const int row = v >> 2;          // 0..127
            const int kk = (v & 3) << 2;     // 0,4,8,12
            f4 a4 = *(const f4*)(A + (size_t)(bm + row) * K + k0 + kk);
            f4 b4 = *(const f4*)(B + (size_t)(bn + row) * K + k0 + kk);
            As[kk + 0][row] = a4[0]; As[kk + 1][row] = a4[1];
            As[kk + 2][row] = a4[2]; As[kk + 3][row] = a4[3];
            Bs[kk + 0][row] = b4[0]; Bs[kk + 1][row] = b4[1];
            Bs[kk + 2][row] = b4[2]; Bs[kk + 3][row] = b4[3];
        }
        __syncthreads();
#pragma unroll
        for (int kk = 0; kk < 16; kk++) {
            f4 a0 = *(const f4*)&As[kk][row0];
            f4 a1 = *(const f4*)&As[kk][row0 + 4];
            f4 b0 = *(const f4*)&Bs[kk][col0];
            f4 b1 = *(const f4*)&Bs[kk][col0 + 4];
            float a[8] = {a0[0], a0[1], a0[2], a0[3], a1[0], a1[1], a1[2], a1[3]};
            float b[8] = {b0[0], b0[1], b0[2], b0[3], b1[0], b1[1], b1[2], b1[3]};
#pragma unroll
            for (int i = 0; i < 8; i++)
#pragma unroll
                for (int j = 0; j < 8; j++) acc[i][j] += a[i] * b[j];
        }
        __syncthreads();
    }

#pragma unroll
    for (int i = 0; i < 8; i++) {
        f4 c0 = {acc[i][0], acc[i][1], acc[i][2], acc[i][3]};
        f4 c1 = {acc[i][4], acc[i][5], acc[i][6], acc[i][7]};
        float* cp = C + (size_t)(bm + row0 + i) * N + bn + col0;
        *(f4*)cp = c0;
        *(f4*)(cp + 4) = c1;
    }
}

// ---------------------------------------------------------------------------
// SuRoPE + reshape [L,OP] -> Q/K/V [H][L][HD]; folds ATTN_SCALE into Q.
// One thread per element of {q,k,v}.
// ---------------------------------------------------------------------------
__global__ void rope_reshape(const float* __restrict__ qkv,
                             const float* __restrict__ sf,
                             float* __restrict__ Qr, float* __restrict__ Kr,
                             float* __restrict__ Vr,
                             float rope_scale, float attn_scale) {
    int idx = blockIdx.x * blockDim.x + threadIdx.x;
    const int d = idx % HDIM;
    int r = idx / HDIM;
    const int l = r % L_SEQ;
    r /= L_SEQ;
    const int h = r % NH;
    const int which = r / NH;  // 0=q 1=k 2=v

    const size_t src_base = (size_t)l * OPROJ + (size_t)which * 3072 + h * HDIM;
    const float val = qkv[src_base + d];
    const size_t dst = ((size_t)h * L_SEQ + l) * HDIM + d;

    if (which == 2) {
        Vr[dst] = val;
        return;
    }
    const int j = (d < 48) ? d : d - 48;
    // match jnp: inv_freq = 1/(sf * theta^(2j/96)); freqs = l * inv_freq
    const float e = (float)(2 * j) / 96.0f;
    const float inv = 1.0f / (sf[j] * powf(10000.0f, e));
    const float ang = (float)l * inv;
    const float cv = cosf(ang) * rope_scale;
    const float sv = sinf(ang) * rope_scale;
    const float pair = qkv[src_base + ((d < 48) ? d + 48 : d - 48)];
    const float rot = (d < 48) ? -pair : pair;
    float out = val * cv + rot * sv;
    if (which == 0) {
        out *= attn_scale;
        Qr[dst] = out;
    } else {
        Kr[dst] = out;
    }
}

// ---------------------------------------------------------------------------
// Flash-style causal attention, fp32 vector ALU.
// Block = 256 threads = one (head, 64-row q-tile). K/V tiles of 64.
// Q LDS pad->100 (2-way reads), K stored transposed [96][68], V [64][96],
// P [64][68]. Online softmax; O accumulated in registers (4 rows x 6 dims).
// ---------------------------------------------------------------------------
__global__ __launch_bounds__(256, 1) void attn_fwd(const float* __restrict__ Q,
                                                   const float* __restrict__ K,
                                                   const float* __restrict__ V,
                                                   float* __restrict__ O) {
    const int h = blockIdx.y;
    const int qt = gridDim.x - 1 - blockIdx.x;  // heavy blocks first
    const int q0 = qt * 64;

    __shared__ float Qs[64][100];
    __shared__ float KsT[96][68];
    __shared__ float Vs[64][96];
    __shared__ float Ps[64][68];

    const int t = threadIdx.x;
    const int g = t >> 4;       // 0..15 -> rows g*4..g*4+3
    const int c = t & 15;       // col group
    const int r0 = g * 4;
    const int c0 = c * 4;       // S cols
    const int d0 = c * 6;       // PV dims

    // stage Q once (already rope'd and attn-scaled)
    const float* Qg = Q + ((size_t)h * L_SEQ + q0) * HDIM;
#pragma unroll
    for (int i = 0; i < 6; i++) {
        const int v = t + i * 256;
        const int row = v / 24;
        const int d4 = v % 24;
        *(f4*)&Qs[row][d4 * 4] = *(const f4*)(Qg + row * HDIM + d4 * 4);
    }

    float o[4][6] = {};
    float m_i[4] = {-1e30f, -1e30f, -1e30f, -1e30f};
    float l_i[4] = {};

    const int nkt = qt + 1;
    for (int kt = 0; kt < nkt; kt++) {
        const int kc0 = kt * 64;
        const float* Kg = K + ((size_t)h * L_SEQ + kc0) * HDIM;
        const float* Vg = V + ((size_t)h * L_SEQ + kc0) * HDIM;
        __syncthreads();  // previous iter's readers of KsT/Vs/Ps done
#pragma unroll
        for (int i = 0; i < 6; i++) {
            const int v = t + i * 256;
            const int row = v / 24;
            const int d4 = v % 24;
            f4 k4 = *(const f4*)(Kg + row * HDIM + d4 * 4);
            KsT[d4 * 4 + 0][row] = k4[0];
            KsT[d4 * 4 + 1][row] = k4[1];
            KsT[d4 * 4 + 2][row] = k4[2];
            KsT[d4 * 4 + 3][row] = k4[3];
            *(f4*)&Vs[row][d4 * 4] = *(const f4*)(Vg + row * HDIM + d4 * 4);
        }
        __syncthreads();

        // S = Q K^T  (4x4 per thread over K=96)
        float s[4][4] = {};
        for (int d4 = 0; d4 < 24; d4++) {
            f4 qv[4], kv[4];
#pragma unroll
            for (int i = 0; i < 4; i++) qv[i] = *(const f4*)&Qs[r0 + i][d4 * 4];
#pragma unroll
            for (int e = 0; e < 4; e++) kv[e] = *(const f4*)&KsT[d4 * 4 + e][c0];
#pragma unroll
            for (int i = 0; i < 4; i++)
#pragma unroll
                for (int j = 0; j < 4; j++)
                    s[i][j] += qv[i][0] * kv[0][j] + qv[i][1] * kv[1][j] +
                               qv[i][2] * kv[2][j] + qv[i][3] * kv[3][j];
        }

        if (kt == qt) {  // diagonal tile: causal mask
#pragma unroll
            for (int i = 0; i < 4; i++)
#pragma unroll
                for (int j = 0; j < 4; j++)
                    if (kc0 + c0 + j > q0 + r0 + i) s[i][j] = -1e30f;
        }

        // online softmax bookkeeping (row stats across the 16-lane c-groups)
        float sc[4];
#pragma unroll
        for (int i = 0; i < 4; i++) {
            float mm = fmaxf(fmaxf(s[i][0], s[i][1]), fmaxf(s[i][2], s[i][3]));
#pragma unroll
            for (int msk = 1; msk < 16; msk <<= 1)
                mm = fmaxf(mm, __shfl_xor(mm, msk, 64));
            const float newm = fmaxf(m_i[i], mm);
            sc[i] = __expf(m_i[i] - newm);
            m_i[i] = newm;
            const float p0 = __expf(s[i][0] - newm);
            const float p1 = __expf(s[i][1] - newm);
            const float p2 = __expf(s[i][2] - newm);
            const float p3 = __expf(s[i][3] - newm);
            Ps[r0 + i][c0 + 0] = p0;
            Ps[r0 + i][c0 + 1] = p1;
            Ps[r0 + i][c0 + 2] = p2;
            Ps[r0 + i][c0 + 3] = p3;
            float ss = p0 + p1 + p2 + p3;
#pragma unroll
            for (int msk = 1; msk < 16; msk <<= 1) ss += __shfl_xor(ss, msk, 64);
            l_i[i] = l_i[i] * sc[i] + ss;
        }
        __syncthreads();

        // O = O*scale + P @ V   (4 rows x 6 dims per thread)
#pragma unroll
        for (int i = 0; i < 4; i++)
#pragma unroll
            for (int j = 0; j < 6; j++) o[i][j] *= sc[i];

        for (int kk = 0; kk < 64; kk++) {
            float p[4];
#pragma unroll
            for (int i = 0; i < 4; i++) p[i] = Ps[r0 + i][kk];
            f2 v0 = *(const f2*)&Vs[kk][d0];
            f2 v1 = *(const f2*)&Vs[kk][d0 + 2];
            f2 v2 = *(const f2*)&Vs[kk][d0 + 4];
            const float vv[6] = {v0[0], v0[1], v1[0], v1[1], v2[0], v2[1]};
#pragma unroll
            for (int i = 0; i < 4; i++)
#pragma unroll
                for (int j = 0; j < 6; j++) o[i][j] += p[i] * vv[j];
        }
    }

    // epilogue: O[l][h*96+d] = o / l_i
#pragma unroll
    for (int i = 0; i < 4; i++) {
        const float inv = 1.0f / l_i[i];
        float* op = O + (size_t)(q0 + r0 + i) * (NH * HDIM) + h * HDIM + d0;
#pragma unroll
        for (int j = 0; j < 6; j++) op[j] = o[i][j] * inv;
    }
}

// ---------------------------------------------------------------------------
extern "C" void kernel_launch(void* const* d_in, const int* in_sizes, int n_in,
                              void* d_out, int out_size, void* d_ws, size_t ws_size,
                              hipStream_t stream) {
    const float* x = (const float*)d_in[0];        // [2048][3072]
    const float* w_qkv = (const float*)d_in[1];    // [9216][3072]
    const float* w_o = (const float*)d_in[2];      // [3072][3072]
    const float* sf = (const float*)d_in[3];       // [48]
    float* out = (float*)d_out;                    // [2048][3072]
    float* ws = (float*)d_ws;

    float* qkv = ws;                               // 2048*9216 = 18,874,368 floats
    float* Qr = ws + (size_t)18874368;             // 32*2048*96 = 6,291,456
    float* Kr = Qr + (size_t)6291456;
    float* Vr = Kr + (size_t)6291456;
    float* Ob = ws;                                // alias qkv (dead after rope)

    const float rope_scale = (float)sqrt(1.0 + log(131072.0 / 4096.0) / log(4096.0));
    const float attn_scale = (float)(1.0 / sqrt(96.0));

    dim3 blk(256);
    // qkv = x @ w_qkv^T : M=2048, N=9216, K=3072
    sgemm_nt<<<dim3(9216 / 128, 2048 / 128), blk, 0, stream>>>(x, w_qkv, qkv, 2048, 9216, 3072);
    // rope + reshape
    const int total = 3 * NH * L_SEQ * HDIM;  // 18,874,368
    rope_reshape<<<total / 256, blk, 0, stream>>>(qkv, sf, Qr, Kr, Vr, rope_scale, attn_scale);
    // attention
    attn_fwd<<<dim3(L_SEQ / 64, NH), blk, 0, stream>>>(Qr, Kr, Vr, Ob);
    // out = O @ w_o^T : M=2048, N=3072, K=3072
    sgemm_nt<<<dim3(3072 / 128, 2048 / 128), blk, 0, stream>>>(Ob, w_o, out, 2048, 3072, 3072);
}

// Round 3
// 840.053 us; speedup vs baseline: 3.8961x; 3.8961x over previous
//
#include <hip/hip_runtime.h>
#include <math.h>

typedef __attribute__((ext_vector_type(4))) float f32x4;
typedef __attribute__((ext_vector_type(4))) float f4;
typedef __attribute__((ext_vector_type(8))) __bf16 bf16x8;
typedef __attribute__((ext_vector_type(8))) unsigned short us8;
typedef __attribute__((ext_vector_type(4))) unsigned short us4;

static __device__ __forceinline__ unsigned short f2bf(float f) {
    union { float f; unsigned u; } v; v.f = f;
    unsigned r = v.u + 0x7FFFu + ((v.u >> 16) & 1u);
    return (unsigned short)(r >> 16);
}
static __device__ __forceinline__ float bf2f(unsigned short b) {
    union { unsigned u; float f; } v; v.u = ((unsigned)b) << 16;
    return v.f;
}
static __device__ __forceinline__ bf16x8 ld8(const unsigned short* p) {
    return __builtin_bit_cast(bf16x8, *(const us8*)p);
}
static __device__ __forceinline__ void glds16(const void* g, void* l) {
    __builtin_amdgcn_global_load_lds((const __attribute__((address_space(1))) unsigned int*)g,
                                     (__attribute__((address_space(3))) unsigned int*)l, 16, 0, 0);
}

// ---------------------------------------------------------------------------
// fp32 -> (hi,lo) bf16 planes, 4 elements/thread
// ---------------------------------------------------------------------------
__global__ void convert_split(const float* __restrict__ in, unsigned short* __restrict__ hi,
                              unsigned short* __restrict__ lo, int n4) {
    int i = blockIdx.x * blockDim.x + threadIdx.x;
    if (i >= n4) return;
    f4 v = *(const f4*)(in + (size_t)i * 4);
    us4 h, l;
#pragma unroll
    for (int j = 0; j < 4; j++) {
        unsigned short hb = f2bf(v[j]);
        h[j] = hb;
        l[j] = f2bf(v[j] - bf2f(hb));
    }
    *(us4*)(hi + (size_t)i * 4) = h;
    *(us4*)(lo + (size_t)i * 4) = l;
}

// ---------------------------------------------------------------------------
// C = A @ B^T in split-bf16 (3 MFMA per product): A[M][K], B[N][K], C[M][N] fp32
// 128x128 tile, BK=32, 4 waves (2x2), 64x64 per wave, global_load_lds staging.
// ---------------------------------------------------------------------------
__global__ __launch_bounds__(256, 2) void gemm_bf16x3(
    const unsigned short* __restrict__ Ah, const unsigned short* __restrict__ Al,
    const unsigned short* __restrict__ Bh, const unsigned short* __restrict__ Bl,
    float* __restrict__ C, int M, int N, int K) {
    __shared__ unsigned short Ash[128][32], Asl[128][32], Bsh[128][32], Bsl[128][32];
    const int t = threadIdx.x;
    const int lane = t & 63, w = t >> 6;
    const int bm = blockIdx.y * 128, bn = blockIdx.x * 128;
    const int wy = w >> 1, wx = w & 1;
    const int l15 = lane & 15, l4 = lane >> 4;

    f32x4 acc[4][4] = {};

    for (int k0 = 0; k0 < K; k0 += 32) {
#pragma unroll
        for (int i = 0; i < 2; i++) {
            const int c = (w * 2 + i) * 64 + lane;
            const int row = c >> 2, seg = (c & 3) * 8;
            const size_t ga = (size_t)(bm + row) * K + k0 + seg;
            const size_t gb = (size_t)(bn + row) * K + k0 + seg;
            const int lo = (w * 2 + i) * 512;  // ushort offset = chunk*8
            glds16(Ah + ga, &Ash[0][0] + lo);
            glds16(Al + ga, &Asl[0][0] + lo);
            glds16(Bh + gb, &Bsh[0][0] + lo);
            glds16(Bl + gb, &Bsl[0][0] + lo);
        }
        __syncthreads();

        bf16x8 afh[4], afl[4], bfh[4], bfl[4];
#pragma unroll
        for (int m = 0; m < 4; m++) {
            afh[m] = ld8(&Ash[wy * 64 + m * 16 + l15][l4 * 8]);
            afl[m] = ld8(&Asl[wy * 64 + m * 16 + l15][l4 * 8]);
        }
#pragma unroll
        for (int n = 0; n < 4; n++) {
            bfh[n] = ld8(&Bsh[wx * 64 + n * 16 + l15][l4 * 8]);
            bfl[n] = ld8(&Bsl[wx * 64 + n * 16 + l15][l4 * 8]);
        }
#pragma unroll
        for (int m = 0; m < 4; m++)
#pragma unroll
            for (int n = 0; n < 4; n++) {
                acc[m][n] = __builtin_amdgcn_mfma_f32_16x16x32_bf16(afh[m], bfh[n], acc[m][n], 0, 0, 0);
                acc[m][n] = __builtin_amdgcn_mfma_f32_16x16x32_bf16(afl[m], bfh[n], acc[m][n], 0, 0, 0);
                acc[m][n] = __builtin_amdgcn_mfma_f32_16x16x32_bf16(afh[m], bfl[n], acc[m][n], 0, 0, 0);
            }
        __syncthreads();
    }

#pragma unroll
    for (int m = 0; m < 4; m++)
#pragma unroll
        for (int n = 0; n < 4; n++)
#pragma unroll
            for (int r = 0; r < 4; r++)
                C[(size_t)(bm + wy * 64 + m * 16 + l4 * 4 + r) * N + bn + wx * 64 + n * 16 + l15] =
                    acc[m][n][r];
}

// ---------------------------------------------------------------------------
// SuRoPE on q,k from fused qkv; outputs split-bf16 planes [H][L][96].
// ATTN_SCALE folded into Q before split.
// ---------------------------------------------------------------------------
__global__ void rope_split(const float* __restrict__ qkv, const float* __restrict__ sf,
                           unsigned short* __restrict__ Qh, unsigned short* __restrict__ Ql,
                           unsigned short* __restrict__ Kh, unsigned short* __restrict__ Kl,
                           float rope_scale, float attn_scale) {
    int idx = blockIdx.x * blockDim.x + threadIdx.x;  // 2*32*2048*96
    const int d = idx % 96;
    int r = idx / 96;
    const int l = r % 2048; r /= 2048;
    const int h = r % 32;
    const int which = r / 32;  // 0=q, 1=k
    const size_t base = (size_t)l * 9216 + (size_t)which * 3072 + h * 96;
    const float val = qkv[base + d];
    const int j = (d < 48) ? d : d - 48;
    const float e = (float)(2 * j) / 96.0f;
    const float inv = 1.0f / (sf[j] * powf(10000.0f, e));
    const float ang = (float)l * inv;
    const float cv = cosf(ang) * rope_scale;
    const float sv = sinf(ang) * rope_scale;
    const float pair = qkv[base + ((d < 48) ? d + 48 : d - 48)];
    const float rot = (d < 48) ? -pair : pair;
    float out = val * cv + rot * sv;
    if (which == 0) out *= attn_scale;
    unsigned short hb = f2bf(out);
    unsigned short lb = f2bf(out - bf2f(hb));
    const size_t dst = ((size_t)h * 2048 + l) * 96 + d;
    if (which == 0) { Qh[dst] = hb; Ql[dst] = lb; }
    else           { Kh[dst] = hb; Kl[dst] = lb; }
}

// ---------------------------------------------------------------------------
// V transpose: qkv v-part [l][h*96+d] -> Vt[h][d][l] bf16 (hi only)
// ---------------------------------------------------------------------------
__global__ __launch_bounds__(256) void vtrans(const float* __restrict__ qkv,
                                              unsigned short* __restrict__ Vt) {
    __shared__ float tile[64][100];
    const int h = blockIdx.y;
    const int l0 = blockIdx.x * 64;
    const int t = threadIdx.x;
#pragma unroll
    for (int i = 0; i < 6; i++) {
        const int v = t + i * 256;
        const int row = v / 24, seg = v % 24;
        *(f4*)&tile[row][seg * 4] =
            *(const f4*)(qkv + (size_t)(l0 + row) * 9216 + 6144 + h * 96 + seg * 4);
    }
    __syncthreads();
#pragma unroll
    for (int i = 0; i < 3; i++) {
        const int v = t + i * 256;
        const int d = v >> 3, lc = v & 7;
        us8 o;
#pragma unroll
        for (int j = 0; j < 8; j++) o[j] = f2bf(tile[lc * 8 + j][d]);
        *(us8*)(Vt + ((size_t)h * 96 + d) * 2048 + l0 + lc * 8) = o;
    }
}

// ---------------------------------------------------------------------------
// Flash attention, MFMA bf16. Block = (64 q-rows, head), 4 waves x 16 rows.
// QK^T split-3; PV: packed (Phi,Plo) x k-duplicated Vhi in one pass.
// Output written as split-bf16 planes for the projection GEMM.
// ---------------------------------------------------------------------------
__global__ __launch_bounds__(256, 2) void attn_mfma(
    const unsigned short* __restrict__ Qh, const unsigned short* __restrict__ Ql,
    const unsigned short* __restrict__ Kh, const unsigned short* __restrict__ Kl,
    const unsigned short* __restrict__ Vt,
    unsigned short* __restrict__ Ohi, unsigned short* __restrict__ Olo) {
    __shared__ unsigned short Ksh[64][104], Ksl[64][104];
    __shared__ unsigned short Vs[96][136];      // V'[d][2kv+{0,1}] duplicated
    __shared__ unsigned short Ps[4][16][136];   // per wave, packed (hi,lo) per kv

    const int h = blockIdx.y;
    const int qt = (int)gridDim.x - 1 - (int)blockIdx.x;  // heavy blocks first
    const int q0 = qt * 64;
    const int t = threadIdx.x, lane = t & 63, w = t >> 6;
    const int l15 = lane & 15, l4 = lane >> 4;

    bf16x8 qfh[3], qfl[3];
    const size_t qrow = ((size_t)h * 2048 + q0 + w * 16 + l15) * 96;
#pragma unroll
    for (int kc = 0; kc < 3; kc++) {
        qfh[kc] = ld8(Qh + qrow + kc * 32 + l4 * 8);
        qfl[kc] = ld8(Ql + qrow + kc * 32 + l4 * 8);
    }

    f32x4 o[6] = {};
    float m_i[4] = {-1e30f, -1e30f, -1e30f, -1e30f};
    float l_i[4] = {0.f, 0.f, 0.f, 0.f};

    for (int kt = 0; kt <= qt; kt++) {
        const int kv0 = kt * 64;
        __syncthreads();
#pragma unroll
        for (int i = 0; i < 3; i++) {
            const int v = t + i * 256;
            const int row = v / 12, seg = (v % 12) * 8;
            const size_t g = ((size_t)h * 2048 + kv0 + row) * 96 + seg;
            *(us8*)&Ksh[row][seg] = *(const us8*)(Kh + g);
            *(us8*)&Ksl[row][seg] = *(const us8*)(Kl + g);
        }
#pragma unroll
        for (int i = 0; i < 6; i++) {
            const int v = t + i * 256;
            const int d = v >> 4, seg = v & 15;
            us4 x = *(const us4*)(Vt + ((size_t)h * 96 + d) * 2048 + kv0 + seg * 4);
            us8 y;
            y[0] = x[0]; y[1] = x[0]; y[2] = x[1]; y[3] = x[1];
            y[4] = x[2]; y[5] = x[2]; y[6] = x[3]; y[7] = x[3];
            *(us8*)&Vs[d][seg * 8] = y;
        }
        __syncthreads();

        // S = Q K^T (split-3)
        f32x4 s[4] = {};
#pragma unroll
        for (int f = 0; f < 4; f++) {
#pragma unroll
            for (int kc = 0; kc < 3; kc++) {
                bf16x8 kh = ld8(&Ksh[f * 16 + l15][kc * 32 + l4 * 8]);
                bf16x8 kl = ld8(&Ksl[f * 16 + l15][kc * 32 + l4 * 8]);
                s[f] = __builtin_amdgcn_mfma_f32_16x16x32_bf16(qfh[kc], kh, s[f], 0, 0, 0);
                s[f] = __builtin_amdgcn_mfma_f32_16x16x32_bf16(qfl[kc], kh, s[f], 0, 0, 0);
                s[f] = __builtin_amdgcn_mfma_f32_16x16x32_bf16(qfh[kc], kl, s[f], 0, 0, 0);
            }
        }

        if (kt == qt) {  // causal mask on diagonal tile
#pragma unroll
            for (int f = 0; f < 4; f++)
#pragma unroll
                for (int r = 0; r < 4; r++)
                    if (f * 16 + l15 > w * 16 + l4 * 4 + r) s[f][r] = -1e30f;
        }

        // online softmax (rows = l4*4+r, cols spread over l15 and f)
        float pr[4][4], sc[4];
#pragma unroll
        for (int r = 0; r < 4; r++) {
            float mx = fmaxf(fmaxf(s[0][r], s[1][r]), fmaxf(s[2][r], s[3][r]));
#pragma unroll
            for (int msk = 1; msk < 16; msk <<= 1) mx = fmaxf(mx, __shfl_xor(mx, msk, 64));
            const float mnew = fmaxf(m_i[r], mx);
            sc[r] = __expf(m_i[r] - mnew);
            m_i[r] = mnew;
            float ssum = 0.f;
#pragma unroll
            for (int f = 0; f < 4; f++) {
                const float p = __expf(s[f][r] - mnew);
                pr[f][r] = p;
                ssum += p;
            }
#pragma unroll
            for (int msk = 1; msk < 16; msk <<= 1) ssum += __shfl_xor(ssum, msk, 64);
            l_i[r] = l_i[r] * sc[r] + ssum;
        }
#pragma unroll
        for (int f2 = 0; f2 < 6; f2++)
#pragma unroll
            for (int r = 0; r < 4; r++) o[f2][r] *= sc[r];

        // pack P (hi,lo interleaved along doubled-k)
#pragma unroll
        for (int f = 0; f < 4; f++)
#pragma unroll
            for (int r = 0; r < 4; r++) {
                unsigned short hb = f2bf(pr[f][r]);
                unsigned short lb = f2bf(pr[f][r] - bf2f(hb));
                *(unsigned*)&Ps[w][l4 * 4 + r][(f * 16 + l15) * 2] =
                    (unsigned)hb | ((unsigned)lb << 16);
            }

        // O += P' V'   (K = 128 doubled)
#pragma unroll
        for (int kc2 = 0; kc2 < 4; kc2++) {
            bf16x8 pa = ld8(&Ps[w][l15][kc2 * 32 + l4 * 8]);
#pragma unroll
            for (int f2 = 0; f2 < 6; f2++) {
                bf16x8 vb = ld8(&Vs[f2 * 16 + l15][kc2 * 32 + l4 * 8]);
                o[f2] = __builtin_amdgcn_mfma_f32_16x16x32_bf16(pa, vb, o[f2], 0, 0, 0);
            }
        }
    }

    // epilogue: normalize, write split-bf16 O [L][3072]
#pragma unroll
    for (int r = 0; r < 4; r++) {
        const float inv = 1.0f / l_i[r];
        const size_t row = (size_t)(q0 + w * 16 + l4 * 4 + r) * 3072 + h * 96;
#pragma unroll
        for (int f2 = 0; f2 < 6; f2++) {
            const float val = o[f2][r] * inv;
            unsigned short hb = f2bf(val);
            Ohi[row + f2 * 16 + l15] = hb;
            Olo[row + f2 * 16 + l15] = f2bf(val - bf2f(hb));
        }
    }
}

// ---------------------------------------------------------------------------
extern "C" void kernel_launch(void* const* d_in, const int* in_sizes, int n_in,
                              void* d_out, int out_size, void* d_ws, size_t ws_size,
                              hipStream_t stream) {
    const float* x = (const float*)d_in[0];
    const float* w_qkv = (const float*)d_in[1];
    const float* w_o = (const float*)d_in[2];
    const float* sf = (const float*)d_in[3];
    float* out = (float*)d_out;
    char* ws = (char*)d_ws;

    // region A [0, 113246208): wqkv splits; after GEMM1 reused for Q/K/V planes
    unsigned short* wqkvh = (unsigned short*)(ws);
    unsigned short* wqkvl = (unsigned short*)(ws + 56623104);
    unsigned short* Qh = (unsigned short*)(ws);
    unsigned short* Ql = (unsigned short*)(ws + 12582912);
    unsigned short* Kh = (unsigned short*)(ws + 25165824);
    unsigned short* Kl = (unsigned short*)(ws + 37748736);
    unsigned short* Vthi = (unsigned short*)(ws + 50331648);
    // region D [113246208, 188743680): qkv fp32; after rope/vtrans reused:
    float* qkv = (float*)(ws + 113246208);
    unsigned short* Ohi = (unsigned short*)(ws + 113246208);
    unsigned short* Olo = (unsigned short*)(ws + 125829120);
    unsigned short* woh = (unsigned short*)(ws + 138412032);
    unsigned short* wol = (unsigned short*)(ws + 157286400);
    // region E [188743680, 213909504): x splits
    unsigned short* xh = (unsigned short*)(ws + 188743680);
    unsigned short* xl = (unsigned short*)(ws + 201326592);

    const float rope_scale = (float)sqrt(1.0 + log(131072.0 / 4096.0) / log(4096.0));
    const float attn_scale = (float)(1.0 / sqrt(96.0));

    convert_split<<<6144, 256, 0, stream>>>(x, xh, xl, 1572864);
    convert_split<<<27648, 256, 0, stream>>>(w_qkv, wqkvh, wqkvl, 7077888);
    gemm_bf16x3<<<dim3(72, 16), 256, 0, stream>>>(xh, xl, wqkvh, wqkvl, qkv, 2048, 9216, 3072);
    rope_split<<<49152, 256, 0, stream>>>(qkv, sf, Qh, Ql, Kh, Kl, rope_scale, attn_scale);
    vtrans<<<dim3(32, 32), 256, 0, stream>>>(qkv, Vthi);
    convert_split<<<9216, 256, 0, stream>>>(w_o, woh, wol, 2359296);
    attn_mfma<<<dim3(32, 32), 256, 0, stream>>>(Qh, Ql, Kh, Kl, Vthi, Ohi, Olo);
    gemm_bf16x3<<<dim3(24, 16), 256, 0, stream>>>(Ohi, Olo, woh, wol, out, 2048, 3072, 3072);
}

// Round 4
// 503.385 us; speedup vs baseline: 6.5019x; 1.6688x over previous
//
#include <hip/hip_runtime.h>
#include <math.h>

typedef __attribute__((ext_vector_type(4))) float f32x4;
typedef __attribute__((ext_vector_type(4))) float f4;
typedef __attribute__((ext_vector_type(8))) _Float16 h8;
typedef __attribute__((ext_vector_type(8))) unsigned short us8;

static __device__ __forceinline__ h8 ld8h(const _Float16* p) {
    return __builtin_bit_cast(h8, *(const us8*)p);
}
static __device__ __forceinline__ void glds16(const void* g, void* l) {
    __builtin_amdgcn_global_load_lds((const __attribute__((address_space(1))) unsigned int*)g,
                                     (__attribute__((address_space(3))) unsigned int*)l, 16, 0, 0);
}

// ---------------------------------------------------------------------------
// fp32 -> fp16, 8 elements/thread
// ---------------------------------------------------------------------------
__global__ void convert_half(const float* __restrict__ in, _Float16* __restrict__ out, int n8) {
    int i = blockIdx.x * blockDim.x + threadIdx.x;
    if (i >= n8) return;
    f4 v0 = *(const f4*)(in + (size_t)i * 8);
    f4 v1 = *(const f4*)(in + (size_t)i * 8 + 4);
    h8 o;
#pragma unroll
    for (int j = 0; j < 4; j++) {
        o[j] = (_Float16)v0[j];
        o[j + 4] = (_Float16)v1[j];
    }
    *(h8*)(out + (size_t)i * 8) = o;
}

// ---------------------------------------------------------------------------
// C = A @ B^T fp16 MFMA: A[M][K], B[N][K] fp16, C[M][N] fp32
// 128x128 tile, BK=32, 4 waves (2x2), 64x64 per wave, global_load_lds staging.
// ---------------------------------------------------------------------------
__global__ __launch_bounds__(256, 3) void gemm_fp16(
    const _Float16* __restrict__ A, const _Float16* __restrict__ B,
    float* __restrict__ C, int M, int N, int K) {
    __shared__ _Float16 As[128][32], Bs[128][32];
    const int t = threadIdx.x;
    const int lane = t & 63, w = t >> 6;
    const int bm = blockIdx.y * 128, bn = blockIdx.x * 128;
    const int wy = w >> 1, wx = w & 1;
    const int l15 = lane & 15, l4 = lane >> 4;

    f32x4 acc[4][4] = {};

    for (int k0 = 0; k0 < K; k0 += 32) {
#pragma unroll
        for (int i = 0; i < 2; i++) {
            const int c = (w * 2 + i) * 64 + lane;   // chunk 0..511
            const int row = c >> 2, seg = (c & 3) * 8;
            const size_t ga = (size_t)(bm + row) * K + k0 + seg;
            const size_t gb = (size_t)(bn + row) * K + k0 + seg;
            const int lo = c * 8;                    // _Float16 offset
            glds16(A + ga, &As[0][0] + lo);
            glds16(B + gb, &Bs[0][0] + lo);
        }
        __syncthreads();

        h8 af[4], bf[4];
#pragma unroll
        for (int m = 0; m < 4; m++) af[m] = ld8h(&As[wy * 64 + m * 16 + l15][l4 * 8]);
#pragma unroll
        for (int n = 0; n < 4; n++) bf[n] = ld8h(&Bs[wx * 64 + n * 16 + l15][l4 * 8]);
#pragma unroll
        for (int m = 0; m < 4; m++)
#pragma unroll
            for (int n = 0; n < 4; n++)
                acc[m][n] = __builtin_amdgcn_mfma_f32_16x16x32_f16(af[m], bf[n], acc[m][n], 0, 0, 0);
        __syncthreads();
    }

#pragma unroll
    for (int m = 0; m < 4; m++)
#pragma unroll
        for (int n = 0; n < 4; n++)
#pragma unroll
            for (int r = 0; r < 4; r++)
                C[(size_t)(bm + wy * 64 + m * 16 + l4 * 4 + r) * N + bn + wx * 64 + n * 16 + l15] =
                    acc[m][n][r];
}

// ---------------------------------------------------------------------------
// SuRoPE on q,k from fused qkv; fp16 out [H][L][96]; ATTN_SCALE folded into Q.
// ---------------------------------------------------------------------------
__global__ void rope_half(const float* __restrict__ qkv, const float* __restrict__ sf,
                          _Float16* __restrict__ Qh, _Float16* __restrict__ Kh,
                          float rope_scale, float attn_scale) {
    int idx = blockIdx.x * blockDim.x + threadIdx.x;  // 2*32*2048*96
    const int d = idx % 96;
    int r = idx / 96;
    const int l = r % 2048; r /= 2048;
    const int h = r % 32;
    const int which = r / 32;  // 0=q, 1=k
    const size_t base = (size_t)l * 9216 + (size_t)which * 3072 + h * 96;
    const float val = qkv[base + d];
    const int j = (d < 48) ? d : d - 48;
    const float e = (float)(2 * j) / 96.0f;
    const float inv = 1.0f / (sf[j] * powf(10000.0f, e));
    const float ang = (float)l * inv;
    const float cv = cosf(ang) * rope_scale;
    const float sv = sinf(ang) * rope_scale;
    const float pair = qkv[base + ((d < 48) ? d + 48 : d - 48)];
    const float rot = (d < 48) ? -pair : pair;
    float out = val * cv + rot * sv;
    if (which == 0) out *= attn_scale;
    const size_t dst = ((size_t)h * 2048 + l) * 96 + d;
    if (which == 0) Qh[dst] = (_Float16)out;
    else            Kh[dst] = (_Float16)out;
}

// ---------------------------------------------------------------------------
// V transpose: qkv v-part [l][h*96+d] -> Vt[h][d][l] fp16
// ---------------------------------------------------------------------------
__global__ __launch_bounds__(256) void vtrans(const float* __restrict__ qkv,
                                              _Float16* __restrict__ Vt) {
    __shared__ float tile[64][100];
    const int h = blockIdx.y;
    const int l0 = blockIdx.x * 64;
    const int t = threadIdx.x;
#pragma unroll
    for (int i = 0; i < 6; i++) {
        const int v = t + i * 256;
        const int row = v / 24, seg = v % 24;
        *(f4*)&tile[row][seg * 4] =
            *(const f4*)(qkv + (size_t)(l0 + row) * 9216 + 6144 + h * 96 + seg * 4);
    }
    __syncthreads();
#pragma unroll
    for (int i = 0; i < 3; i++) {
        const int v = t + i * 256;
        const int d = v >> 3, lc = v & 7;
        h8 o;
#pragma unroll
        for (int j = 0; j < 8; j++) o[j] = (_Float16)tile[lc * 8 + j][d];
        *(h8*)(Vt + ((size_t)h * 96 + d) * 2048 + l0 + lc * 8) = o;
    }
}

// ---------------------------------------------------------------------------
// Flash attention, fp16 MFMA. Block = (64 q-rows, head), 4 waves x 16 rows.
// ---------------------------------------------------------------------------
__global__ __launch_bounds__(256, 2) void attn_mfma(
    const _Float16* __restrict__ Qh, const _Float16* __restrict__ Kh,
    const _Float16* __restrict__ Vt, _Float16* __restrict__ Oh) {
    __shared__ _Float16 Ks[64][104];
    __shared__ _Float16 Vs[96][72];
    __shared__ _Float16 Ps[4][16][72];

    const int h = blockIdx.y;
    const int qt = (int)gridDim.x - 1 - (int)blockIdx.x;  // heavy blocks first
    const int q0 = qt * 64;
    const int t = threadIdx.x, lane = t & 63, w = t >> 6;
    const int l15 = lane & 15, l4 = lane >> 4;

    h8 qf[3];
    const size_t qrow = ((size_t)h * 2048 + q0 + w * 16 + l15) * 96;
#pragma unroll
    for (int kc = 0; kc < 3; kc++) qf[kc] = ld8h(Qh + qrow + kc * 32 + l4 * 8);

    f32x4 o[6] = {};
    float m_i[4] = {-1e30f, -1e30f, -1e30f, -1e30f};
    float l_i[4] = {0.f, 0.f, 0.f, 0.f};

    for (int kt = 0; kt <= qt; kt++) {
        const int kv0 = kt * 64;
        __syncthreads();
#pragma unroll
        for (int i = 0; i < 3; i++) {
            const int v = t + i * 256;
            const int row = v / 12, seg = (v % 12) * 8;
            *(us8*)&Ks[row][seg] = *(const us8*)(Kh + ((size_t)h * 2048 + kv0 + row) * 96 + seg);
        }
#pragma unroll
        for (int i = 0; i < 3; i++) {
            const int v = t + i * 256;
            const int d = v >> 3, lc = v & 7;
            *(us8*)&Vs[d][lc * 8] = *(const us8*)(Vt + ((size_t)h * 96 + d) * 2048 + kv0 + lc * 8);
        }
        __syncthreads();

        // S = Q K^T
        f32x4 s[4] = {};
#pragma unroll
        for (int f = 0; f < 4; f++)
#pragma unroll
            for (int kc = 0; kc < 3; kc++) {
                h8 kf = ld8h(&Ks[f * 16 + l15][kc * 32 + l4 * 8]);
                s[f] = __builtin_amdgcn_mfma_f32_16x16x32_f16(qf[kc], kf, s[f], 0, 0, 0);
            }

        if (kt == qt) {  // causal mask on diagonal tile
#pragma unroll
            for (int f = 0; f < 4; f++)
#pragma unroll
                for (int r = 0; r < 4; r++)
                    if (f * 16 + l15 > w * 16 + l4 * 4 + r) s[f][r] = -1e30f;
        }

        // online softmax (rows = l4*4+r, cols spread over l15 and f)
        float pr[4][4], sc[4];
#pragma unroll
        for (int r = 0; r < 4; r++) {
            float mx = fmaxf(fmaxf(s[0][r], s[1][r]), fmaxf(s[2][r], s[3][r]));
#pragma unroll
            for (int msk = 1; msk < 16; msk <<= 1) mx = fmaxf(mx, __shfl_xor(mx, msk, 64));
            const float mnew = fmaxf(m_i[r], mx);
            sc[r] = __expf(m_i[r] - mnew);
            m_i[r] = mnew;
            float ssum = 0.f;
#pragma unroll
            for (int f = 0; f < 4; f++) {
                const float p = __expf(s[f][r] - mnew);
                pr[f][r] = p;
                ssum += p;
            }
#pragma unroll
            for (int msk = 1; msk < 16; msk <<= 1) ssum += __shfl_xor(ssum, msk, 64);
            l_i[r] = l_i[r] * sc[r] + ssum;
        }
#pragma unroll
        for (int f2 = 0; f2 < 6; f2++)
#pragma unroll
            for (int r = 0; r < 4; r++) o[f2][r] *= sc[r];

        // store P (fp16)
#pragma unroll
        for (int f = 0; f < 4; f++)
#pragma unroll
            for (int r = 0; r < 4; r++)
                Ps[w][l4 * 4 + r][f * 16 + l15] = (_Float16)pr[f][r];

        // O += P V   (K = 64)
#pragma unroll
        for (int kc2 = 0; kc2 < 2; kc2++) {
            h8 pa = ld8h(&Ps[w][l15][kc2 * 32 + l4 * 8]);
#pragma unroll
            for (int f2 = 0; f2 < 6; f2++) {
                h8 vb = ld8h(&Vs[f2 * 16 + l15][kc2 * 32 + l4 * 8]);
                o[f2] = __builtin_amdgcn_mfma_f32_16x16x32_f16(pa, vb, o[f2], 0, 0, 0);
            }
        }
    }

    // epilogue: normalize, write fp16 O [L][3072]
#pragma unroll
    for (int r = 0; r < 4; r++) {
        const float inv = 1.0f / l_i[r];
        const size_t row = (size_t)(q0 + w * 16 + l4 * 4 + r) * 3072 + h * 96;
#pragma unroll
        for (int f2 = 0; f2 < 6; f2++)
            Oh[row + f2 * 16 + l15] = (_Float16)(o[f2][r] * inv);
    }
}

// ---------------------------------------------------------------------------
extern "C" void kernel_launch(void* const* d_in, const int* in_sizes, int n_in,
                              void* d_out, int out_size, void* d_ws, size_t ws_size,
                              hipStream_t stream) {
    const float* x = (const float*)d_in[0];
    const float* w_qkv = (const float*)d_in[1];
    const float* w_o = (const float*)d_in[2];
    const float* sf = (const float*)d_in[3];
    float* out = (float*)d_out;
    char* ws = (char*)d_ws;

    // region A [0, 56.6MB): wqkv fp16; dead after GEMM1, reused for Q/K/V/O
    _Float16* wqkvh = (_Float16*)(ws);
    _Float16* Qh = (_Float16*)(ws);
    _Float16* Kh = (_Float16*)(ws + 12582912);
    _Float16* Vth = (_Float16*)(ws + 25165824);
    _Float16* Oh = (_Float16*)(ws + 37748736);
    // region B: qkv fp32
    float* qkv = (float*)(ws + 56623104);
    // region C: x fp16
    _Float16* xh = (_Float16*)(ws + 132120576);
    // region D: w_o fp16
    _Float16* woh = (_Float16*)(ws + 144703488);

    const float rope_scale = (float)sqrt(1.0 + log(131072.0 / 4096.0) / log(4096.0));
    const float attn_scale = (float)(1.0 / sqrt(96.0));

    convert_half<<<3072, 256, 0, stream>>>(x, xh, 786432);
    convert_half<<<13824, 256, 0, stream>>>(w_qkv, wqkvh, 3538944);
    gemm_fp16<<<dim3(72, 16), 256, 0, stream>>>(xh, wqkvh, qkv, 2048, 9216, 3072);
    rope_half<<<49152, 256, 0, stream>>>(qkv, sf, Qh, Kh, rope_scale, attn_scale);
    vtrans<<<dim3(32, 32), 256, 0, stream>>>(qkv, Vth);
    convert_half<<<4608, 256, 0, stream>>>(w_o, woh, 1179648);
    attn_mfma<<<dim3(32, 32), 256, 0, stream>>>(Qh, Kh, Vth, Oh);
    gemm_fp16<<<dim3(24, 16), 256, 0, stream>>>(Oh, woh, out, 2048, 3072, 3072);
}